// Round 3
// baseline (7253.986 us; speedup 1.0000x reference)
//
#include <hip/hip_runtime.h>
#include <hip/hip_bf16.h>
#include <stdint.h>

#define B_  2048
#define D_  512
#define M_  32768
#define H_  4
#define HD_ 128
#define K_  64
#define MS_ 4               // M-split factor for scores_topk occupancy
#define SLICE_ (M_ / MS_)   // 8192 candidates per WG

// ---------------------------------------------------------------------------
// GEMM: C[n][o] = sum_j X[n][j] * W[o][j] + bias[o]   (all fp32, NT layout)
// ---------------------------------------------------------------------------
__global__ __launch_bounds__(256) void gemm_nt_bias(
    const float* __restrict__ X, const float* __restrict__ W,
    const float* __restrict__ bias, float* __restrict__ C, int N) {
  __shared__ float As[16][132];
  __shared__ float Bs[16][132];
  const int t  = threadIdx.x;
  const int tx = t & 15, ty = t >> 4;
  const int rowbase = blockIdx.x * 128;
  const int colbase = blockIdx.y * 128;
  float acc[8][8];
  #pragma unroll
  for (int i = 0; i < 8; ++i)
    #pragma unroll
    for (int j = 0; j < 8; ++j) acc[i][j] = 0.f;

  for (int k0 = 0; k0 < 512; k0 += 16) {
    #pragma unroll
    for (int i = 0; i < 2; ++i) {
      int idx = t + i * 256;
      int r = idx >> 2, kq = idx & 3;
      float4 v = *(const float4*)&X[(size_t)(rowbase + r) * 512 + k0 + kq * 4];
      As[kq*4+0][r] = v.x; As[kq*4+1][r] = v.y;
      As[kq*4+2][r] = v.z; As[kq*4+3][r] = v.w;
      float4 w = *(const float4*)&W[(size_t)(colbase + r) * 512 + k0 + kq * 4];
      Bs[kq*4+0][r] = w.x; Bs[kq*4+1][r] = w.y;
      Bs[kq*4+2][r] = w.z; Bs[kq*4+3][r] = w.w;
    }
    __syncthreads();
    #pragma unroll
    for (int k = 0; k < 16; ++k) {
      float a[8], b[8];
      *(float4*)&a[0] = *(const float4*)&As[k][ty*8];
      *(float4*)&a[4] = *(const float4*)&As[k][ty*8+4];
      *(float4*)&b[0] = *(const float4*)&Bs[k][tx*8];
      *(float4*)&b[4] = *(const float4*)&Bs[k][tx*8+4];
      #pragma unroll
      for (int i = 0; i < 8; ++i)
        #pragma unroll
        for (int j = 0; j < 8; ++j)
          acc[i][j] = fmaf(a[i], b[j], acc[i][j]);
    }
    __syncthreads();
  }
  #pragma unroll
  for (int i = 0; i < 8; ++i) {
    size_t r = (size_t)(rowbase + ty*8 + i);
    #pragma unroll
    for (int j4 = 0; j4 < 2; ++j4) {
      int c = colbase + tx*8 + j4*4;
      float4 bv = *(const float4*)&bias[c];
      float4 o;
      o.x = acc[i][j4*4+0] + bv.x;
      o.y = acc[i][j4*4+1] + bv.y;
      o.z = acc[i][j4*4+2] + bv.z;
      o.w = acc[i][j4*4+3] + bv.w;
      *(float4*)&C[r * 512 + c] = o;
    }
  }
}

// ---------------------------------------------------------------------------
// Fused scores + running top-64 over an M-slice.
// Grid (B/32, H, MS_), 256 threads (4 waves). Wave w owns 8 q-rows.
// K chunks (64 cands x 128 dims fp32) staged via global_load_lds (16B, no
// VGPR round-trip) into double-buffered LDS. XOR swizzle achieved by
// pre-swizzling the per-lane GLOBAL address; LDS dest stays linear (rule 21).
// Per-slice top-64 lists in registers (lane <-> slot), ballot-gated insert.
// Tie-breaking matches jax.lax.top_k (keep lowest index).
// ---------------------------------------------------------------------------
__global__ __launch_bounds__(256) void scores_topk(
    const float* __restrict__ Qp, const float* __restrict__ Kp,
    float* __restrict__ tks, int* __restrict__ tki) {
  __shared__ __align__(16) float Ks[2][64 * 128];   // 2 x 32 KB
  const int t    = threadIdx.x;
  const int wid  = t >> 6, lane = t & 63;
  const int h    = blockIdx.y;
  const int rowbase = blockIdx.x * 32;
  const int mbase = blockIdx.z * SLICE_;
  const int mend  = mbase + SLICE_;
  // force SGPR (uniform) base for Q so the compiler emits s_load
  const int rb = __builtin_amdgcn_readfirstlane(rowbase + wid * 8);
  const float* qb = Qp + (size_t)rb * 512 + (size_t)h * 128;
  const size_t kcol = (size_t)h * 128;

  // Stage one 64-cand chunk (32 KB) into Ks[buf]. Wave w covers candidates
  // w*16 .. w*16+15 (its 8 KB LDS region), 8 issues of 1 KB per wave.
  // LDS slot (c, bd') holds global dim-block bd = bd' ^ (c&7).
  auto stage = [&](int mb, int buf) {
    #pragma unroll
    for (int i = 0; i < 8; ++i) {
      int c  = (wid << 4) + (i << 1) + (lane >> 5);
      int bd = (lane & 31) ^ (c & 7);
      const float* g = Kp + (size_t)(mb + c) * 512 + kcol + (size_t)(bd << 2);
      char* lbase = (char*)&Ks[0][0] + (buf << 15) + (wid << 13) + (i << 10);
      __builtin_amdgcn_global_load_lds(
          (const __attribute__((address_space(1))) void*)g,
          (__attribute__((address_space(3))) void*)lbase, 16, 0, 0);
    }
  };

  float ls[8], thr[8];
  int   li[8];
  const int lb = lane & 7;
  const float SCALE = 0.08838834764831843f; // 1/sqrt(128)

  stage(mbase, 0);
  int cur = 0;

  for (int mb = mbase; mb < mend; mb += 64) {
    const bool more = (mb + 64) < mend;
    if (more) {
      stage(mb + 64, cur ^ 1);                     // prefetch next chunk
      asm volatile("s_waitcnt vmcnt(8)" ::: "memory");  // cur's 8 loads done
    } else {
      asm volatile("s_waitcnt vmcnt(0)" ::: "memory");
    }
    __syncthreads();   // all waves' stages for cur visible

    float acc[8];
    #pragma unroll
    for (int r = 0; r < 8; ++r) acc[r] = 0.f;

    const float* ksb = &Ks[cur][0];
    #pragma unroll 2
    for (int db = 0; db < 32; db += 4) {
      float kk[16];
      #pragma unroll
      for (int u = 0; u < 4; ++u)
        *(float4*)&kk[u * 4] =
            *(const float4*)&ksb[(lane << 7) + (((db + u) ^ lb) << 2)];
      #pragma unroll
      for (int j = 0; j < 16; ++j) {
        #pragma unroll
        for (int r = 0; r < 8; ++r)
          acc[r] = fmaf(qb[r * 512 + db * 4 + j], kk[j], acc[r]);
      }
    }

    if (mb == mbase) {
      // first chunk exactly fills the 64-entry list
      #pragma unroll
      for (int r = 0; r < 8; ++r) {
        float s = acc[r] * SCALE;
        ls[r] = s; li[r] = mbase + lane;
        float m = s;
        #pragma unroll
        for (int off = 32; off; off >>= 1) m = fminf(m, __shfl_xor(m, off));
        thr[r] = m;
      }
    } else {
      #pragma unroll
      for (int r = 0; r < 8; ++r) {
        float s = acc[r] * SCALE;
        unsigned long long mask = __ballot(s > thr[r]);
        if (mask) {
          do {
            int src = __ffsll((long long)mask) - 1; mask &= mask - 1;
            float cs = __shfl(s, src);
            int   cm = mb + src;
            // argmin over list; tie -> evict larger index (keep lower index)
            float bs = ls[r]; int bi = li[r]; int bp = lane;
            #pragma unroll
            for (int off = 32; off; off >>= 1) {
              float os = __shfl_xor(bs, off);
              int   oi = __shfl_xor(bi, off);
              int   op = __shfl_xor(bp, off);
              if (os < bs || (os == bs && oi > bi)) { bs = os; bi = oi; bp = op; }
            }
            if (cs > bs && lane == bp) { ls[r] = cs; li[r] = cm; }
          } while (mask);
          float m2 = ls[r];
          #pragma unroll
          for (int off = 32; off; off >>= 1) m2 = fminf(m2, __shfl_xor(m2, off));
          thr[r] = m2;
        }
      }
    }

    __syncthreads();   // all waves done reading cur before it is re-staged
    cur ^= 1;
  }

  #pragma unroll
  for (int r = 0; r < 8; ++r) {
    size_t o = ((((size_t)(rowbase + wid * 8 + r)) * H_ + h) * MS_ + blockIdx.z) * 64 + lane;
    tks[o] = ls[r];
    tki[o] = li[r];
  }
}

// ---------------------------------------------------------------------------
// Merge MS_*64 = 256 per-slice candidates -> top-64, per (b,h).
// Bitonic sort by (score desc, idx asc) == jax.lax.top_k semantics.
// ---------------------------------------------------------------------------
__global__ __launch_bounds__(128) void topk_merge(
    const float* __restrict__ tks, const int* __restrict__ tki,
    float* __restrict__ mtks, int* __restrict__ mtki) {
  __shared__ float s_[256];
  __shared__ int   i_[256];
  const int bh = blockIdx.x;
  const int t  = threadIdx.x;
  s_[t]       = tks[(size_t)bh * 256 + t];
  i_[t]       = tki[(size_t)bh * 256 + t];
  s_[t + 128] = tks[(size_t)bh * 256 + t + 128];
  i_[t + 128] = tki[(size_t)bh * 256 + t + 128];
  __syncthreads();
  for (int k = 2; k <= 256; k <<= 1) {
    for (int j = k >> 1; j > 0; j >>= 1) {
      int i = ((t & ~(j - 1)) << 1) | (t & (j - 1));
      int p = i | j;
      bool dir = ((i & k) == 0);
      float sa = s_[i], sb = s_[p];
      int   ia = i_[i], ib = i_[p];
      bool inorder = (sa > sb) || (sa == sb && ia <= ib);
      if (inorder != dir) { s_[i] = sb; s_[p] = sa; i_[i] = ib; i_[p] = ia; }
      __syncthreads();
    }
  }
  if (t < 64) {
    mtks[(size_t)bh * 64 + t] = s_[t];
    mtki[(size_t)bh * 64 + t] = i_[t];
  }
}

// ---------------------------------------------------------------------------
// Softmax over top-64 + V gather + weighted sum.  Grid (B*H), 128 threads.
// ---------------------------------------------------------------------------
__global__ __launch_bounds__(128) void attend(
    const float* __restrict__ mtks, const int* __restrict__ mtki,
    const float* __restrict__ Vp, float* __restrict__ att) {
  __shared__ float wsm[64];
  __shared__ int   widx[64];
  const int bh = blockIdx.x;
  const int b = bh >> 2, h = bh & 3;
  const int t = threadIdx.x;
  if (t < 64) {
    float s = mtks[(size_t)bh * 64 + t];
    float m = s;
    #pragma unroll
    for (int off = 32; off; off >>= 1) m = fmaxf(m, __shfl_xor(m, off));
    float e = expf(s - m);
    float z = e;
    #pragma unroll
    for (int off = 32; off; off >>= 1) z += __shfl_xor(z, off);
    wsm[t]  = e / z;
    widx[t] = mtki[(size_t)bh * 64 + t];
  }
  __syncthreads();
  float a = 0.f;
  #pragma unroll 4
  for (int k = 0; k < 64; ++k)
    a = fmaf(wsm[k], Vp[(size_t)widx[k] * 512 + h * 128 + t], a);
  att[(size_t)b * 512 + h * 128 + t] = a;
}

// ---------------------------------------------------------------------------
extern "C" void kernel_launch(void* const* d_in, const int* in_sizes, int n_in,
                              void* d_out, int out_size, void* d_ws, size_t ws_size,
                              hipStream_t stream) {
  const float* query  = (const float*)d_in[0];
  const float* memory = (const float*)d_in[1];
  const float* Wq = (const float*)d_in[2];
  const float* bq = (const float*)d_in[3];
  const float* Wk = (const float*)d_in[4];
  const float* bk = (const float*)d_in[5];
  const float* Wv = (const float*)d_in[6];
  const float* bv = (const float*)d_in[7];
  const float* Wo = (const float*)d_in[8];
  const float* bo = (const float*)d_in[9];
  float* out = (float*)d_out;

  // workspace layout (fp32 elements)
  float* Qp  = (float*)d_ws;                        //  2048*512      (4 MB)
  float* Kp  = Qp  + (size_t)B_ * D_;               // 32768*512     (64 MB)
  float* Vp  = Kp  + (size_t)M_ * D_;               // 32768*512     (64 MB)
  float* att = Vp  + (size_t)M_ * D_;               //  2048*512      (4 MB)
  float* tks = att + (size_t)B_ * D_;               //  B*H*MS*64     (8 MB)
  int*   tki = (int*)(tks + (size_t)B_ * H_ * MS_ * K_);            // (8 MB)
  // merged lists alias Qp's space (Qp dead after scores_topk): 4 MB needed
  float* mtks = Qp;                                  // B*H*64 (2 MB)
  int*   mtki = (int*)(mtks + (size_t)B_ * H_ * K_); //        (2 MB)

  gemm_nt_bias<<<dim3(B_ / 128, 4), 256, 0, stream>>>(query,  Wq, bq, Qp, B_);
  gemm_nt_bias<<<dim3(M_ / 128, 4), 256, 0, stream>>>(memory, Wk, bk, Kp, M_);
  gemm_nt_bias<<<dim3(M_ / 128, 4), 256, 0, stream>>>(memory, Wv, bv, Vp, M_);
  scores_topk<<<dim3(B_ / 32, H_, MS_), 256, 0, stream>>>(Qp, Kp, tks, tki);
  topk_merge<<<dim3(B_ * H_), 128, 0, stream>>>(tks, tki, mtks, mtki);
  attend<<<dim3(B_ * H_), 128, 0, stream>>>(mtks, mtki, Vp, att);
  gemm_nt_bias<<<dim3(B_ / 128, 4), 256, 0, stream>>>(att, Wo, bo, out, B_);
}

// Round 5
// 1555.617 us; speedup vs baseline: 4.6631x; 4.6631x over previous
//
#include <hip/hip_runtime.h>
#include <hip/hip_bf16.h>
#include <stdint.h>

#define B_  2048
#define D_  512
#define M_  32768
#define H_  4
#define HD_ 128
#define K_  64
#define MS_ 4               // M-split factor
#define SLICE_ (M_ / MS_)   // 8192 candidates per WG
#define CH_ 128             // candidates per chunk (pass 1)

typedef __attribute__((ext_vector_type(8))) short short8;
typedef __attribute__((ext_vector_type(4))) float float4v;

// ---------------------------------------------------------------------------
// GEMM: C[n][o] = sum_j X[n][j] * W[o][j] + bias[o]   (all fp32, NT layout)
// ---------------------------------------------------------------------------
__global__ __launch_bounds__(256) void gemm_nt_bias(
    const float* __restrict__ X, const float* __restrict__ W,
    const float* __restrict__ bias, float* __restrict__ C, int N) {
  __shared__ float As[16][132];
  __shared__ float Bs[16][132];
  const int t  = threadIdx.x;
  const int tx = t & 15, ty = t >> 4;
  const int rowbase = blockIdx.x * 128;
  const int colbase = blockIdx.y * 128;
  float acc[8][8];
  #pragma unroll
  for (int i = 0; i < 8; ++i)
    #pragma unroll
    for (int j = 0; j < 8; ++j) acc[i][j] = 0.f;

  for (int k0 = 0; k0 < 512; k0 += 16) {
    #pragma unroll
    for (int i = 0; i < 2; ++i) {
      int idx = t + i * 256;
      int r = idx >> 2, kq = idx & 3;
      float4 v = *(const float4*)&X[(size_t)(rowbase + r) * 512 + k0 + kq * 4];
      As[kq*4+0][r] = v.x; As[kq*4+1][r] = v.y;
      As[kq*4+2][r] = v.z; As[kq*4+3][r] = v.w;
      float4 w = *(const float4*)&W[(size_t)(colbase + r) * 512 + k0 + kq * 4];
      Bs[kq*4+0][r] = w.x; Bs[kq*4+1][r] = w.y;
      Bs[kq*4+2][r] = w.z; Bs[kq*4+3][r] = w.w;
    }
    __syncthreads();
    #pragma unroll
    for (int k = 0; k < 16; ++k) {
      float a[8], b[8];
      *(float4*)&a[0] = *(const float4*)&As[k][ty*8];
      *(float4*)&a[4] = *(const float4*)&As[k][ty*8+4];
      *(float4*)&b[0] = *(const float4*)&Bs[k][tx*8];
      *(float4*)&b[4] = *(const float4*)&Bs[k][tx*8+4];
      #pragma unroll
      for (int i = 0; i < 8; ++i)
        #pragma unroll
        for (int j = 0; j < 8; ++j)
          acc[i][j] = fmaf(a[i], b[j], acc[i][j]);
    }
    __syncthreads();
  }
  #pragma unroll
  for (int i = 0; i < 8; ++i) {
    size_t r = (size_t)(rowbase + ty*8 + i);
    #pragma unroll
    for (int j4 = 0; j4 < 2; ++j4) {
      int c = colbase + tx*8 + j4*4;
      float4 bv = *(const float4*)&bias[c];
      float4 o;
      o.x = acc[i][j4*4+0] + bv.x;
      o.y = acc[i][j4*4+1] + bv.y;
      o.z = acc[i][j4*4+2] + bv.z;
      o.w = acc[i][j4*4+3] + bv.w;
      *(float4*)&C[r * 512 + c] = o;
    }
  }
}

// ---------------------------------------------------------------------------
// fp32 [nrows][512] -> bf16 per-head [H][nrows][128]
// ---------------------------------------------------------------------------
__global__ __launch_bounds__(256) void to_bf16_heads(
    const float* __restrict__ src, ushort* __restrict__ dst, int nrows) {
  size_t i = (size_t)blockIdx.x * 256 + threadIdx.x;
  size_t total = (size_t)nrows * 64;
  if (i >= total) return;
  size_t m = i >> 6; int g = (int)(i & 63);
  int h = g >> 4, dd = (g & 15) << 3;
  const float* s = &src[m * 512 + (size_t)g * 8];
  ushort u[8] __attribute__((aligned(16)));
  #pragma unroll
  for (int k = 0; k < 8; ++k) {
    union { float f; unsigned v; } cv; cv.f = s[k];
    unsigned r = (cv.v + 0x7fffu + ((cv.v >> 16) & 1u)) >> 16;  // RNE
    u[k] = (ushort)r;
  }
  *(uint4*)&dst[((size_t)h * nrows + m) * 128 + dd] = *(uint4*)u;
}

// ---------------------------------------------------------------------------
// Pass 1: bf16 MFMA scores + per-slice running top-64 (indices only).
// Grid (B/32, H, MS_), 256 threads (4 waves).
// Wave w: q-half (w&1), cand-half (w>>1) of each 32q x 128c chunk.
// MFMA A = K-frags, B = Q-frags -> C: q = lane&15, cand = (lane>>4)*4+reg.
// Chunk scores dumped to XOR-swizzled LDS; selection holds a DESC-sorted
// (score, idx) list across lanes; insert = ballot + shfl_up shift.
// FIX vs R4: re-check cs > thr (current min) before each insert — the
// ballot mask was computed against the OLD threshold; without the re-check
// a candidate below the current min produced pos=-1 and corrupted the list
// (duplicated max, dropped min).
// ---------------------------------------------------------------------------
__global__ __launch_bounds__(256, 4) void scores_topk_mfma(
    const ushort* __restrict__ Qbf, const ushort* __restrict__ Kbf,
    int* __restrict__ tki) {
  __shared__ __align__(16) float S[2][32 * CH_];   // 2 x 16 KB
  const int t = threadIdx.x, w = t >> 6, lane = t & 63;
  const int h = blockIdx.y, z = blockIdx.z;
  const int rowbase = blockIdx.x * 32;
  const int mbase = z * SLICE_;
  const int l15 = lane & 15, l4 = lane >> 4;
  const int qh = w & 1, chh = w >> 1;

  // Q fragments for this wave's 16 q-rows, resident in VGPRs
  const short* Qh = (const short*)Qbf +
      ((size_t)h * B_ + rowbase + 16 * qh + l15) * 128 + l4 * 8;
  short8 qf[4];
  #pragma unroll
  for (int ks = 0; ks < 4; ++ks) qf[ks] = *(const short8*)(Qh + ks * 32);

  const short* Kh = (const short*)Kbf + (size_t)h * M_ * 128;

  float ls[8], thr[8];
  int   li[8];
  #pragma unroll
  for (int r = 0; r < 8; ++r) { ls[r] = -3.0e38f; li[r] = 0; thr[r] = -3.0e38f; }

  int buf = 0;
  for (int mb = mbase; mb < mbase + SLICE_; mb += CH_) {
    // ---- MFMA: 16q x 64c for this wave ----
    #pragma unroll
    for (int tt = 0; tt < 4; ++tt) {
      const short* Ka = Kh + (size_t)(mb + 64 * chh + 16 * tt + l15) * 128 + l4 * 8;
      float4v acc = {0.f, 0.f, 0.f, 0.f};
      #pragma unroll
      for (int ks = 0; ks < 4; ++ks) {
        short8 af = *(const short8*)(Ka + ks * 32);
        acc = __builtin_amdgcn_mfma_f32_16x16x32_bf16(af, qf[ks], acc, 0, 0, 0);
      }
      const int ql   = 16 * qh + l15;
      const int cblk = 16 * chh + 4 * tt + l4;
      *(float4v*)((char*)&S[buf][0] + ql * 512 + ((cblk ^ (ql & 15)) << 4)) = acc;
    }
    __syncthreads();

    // ---- selection: wave w owns rows 8w..8w+7 ----
    #pragma unroll
    for (int r = 0; r < 8; ++r) {
      const int qs = 8 * w + r;
      #pragma unroll
      for (int hf = 0; hf < 2; ++hf) {
        const int c = 64 * hf + lane;
        const int cblk = c >> 2;
        float s = *(const float*)((const char*)&S[buf][0] + qs * 512 +
                                  (((cblk ^ (qs & 15))) << 4) + (c & 3) * 4);
        unsigned long long m = __ballot(s > thr[r]);
        while (m) {
          const int src = __ffsll((long long)m) - 1; m &= m - 1;
          const float cs = __shfl(s, src);
          if (cs > thr[r]) {   // re-check vs CURRENT min (wave-uniform branch)
            const int ci = mb + 64 * hf + src;
            unsigned long long lt = __ballot(ls[r] < cs);
            const int pos = __ffsll((long long)lt) - 1;
            const float ps = __shfl_up(ls[r], 1);
            const int   pi = __shfl_up(li[r], 1);
            if (lane >= pos) {
              ls[r] = (lane == pos) ? cs : ps;
              li[r] = (lane == pos) ? ci : pi;
            }
            thr[r] = __shfl(ls[r], 63);
          }
        }
      }
    }
    buf ^= 1;
  }

  #pragma unroll
  for (int r = 0; r < 8; ++r) {
    size_t o = ((((size_t)(rowbase + 8 * w + r)) * H_ + h) * MS_ + z) * 64 + lane;
    tki[o] = li[r];
  }
}

// ---------------------------------------------------------------------------
// Pass 2 fused: exact fp32 rescore of the 256-union, exact top-64 (bitonic,
// jax tie semantics), softmax, V-gather, attended write.  Grid (B*H), 256t.
// ---------------------------------------------------------------------------
__global__ __launch_bounds__(256) void rescore_attend(
    const float* __restrict__ Qp, const float* __restrict__ Kp,
    const float* __restrict__ Vp, const int* __restrict__ tki,
    float* __restrict__ att) {
  __shared__ float q_[128];
  __shared__ float s_[256];
  __shared__ int   i_[256];
  __shared__ float wsm[64];
  __shared__ int   widx[64];
  const int bh = blockIdx.x, b = bh >> 2, h = bh & 3;
  const int t = threadIdx.x, w = t >> 6, lane = t & 63;
  const float SCALE = 0.08838834764831843f; // 1/sqrt(128)

  if (t < 32) *(float4*)&q_[t * 4] = *(const float4*)&Qp[(size_t)b * 512 + h * 128 + t * 4];
  i_[t] = tki[(size_t)bh * 256 + t];
  __syncthreads();

  // exact rescore: one octet (8 lanes) per candidate
  const int o = lane >> 3, il = lane & 7;
  #pragma unroll 2
  for (int p = 0; p < 8; ++p) {
    const int j = w * 64 + p * 8 + o;
    const int idx = i_[j];
    const float* kr = Kp + (size_t)idx * 512 + h * 128;
    float part = 0.f;
    #pragma unroll
    for (int u = 0; u < 4; ++u) {
      const int f = il + u * 8;
      float4 kv = *(const float4*)&kr[f * 4];
      float4 qv = *(const float4*)&q_[f * 4];
      part += kv.x * qv.x + kv.y * qv.y + kv.z * qv.z + kv.w * qv.w;
    }
    part += __shfl_xor(part, 1);
    part += __shfl_xor(part, 2);
    part += __shfl_xor(part, 4);
    if (il == 0) s_[j] = part * SCALE;
  }
  __syncthreads();

  // bitonic sort 256 by (score desc, idx asc)
  for (int k = 2; k <= 256; k <<= 1) {
    for (int j = k >> 1; j > 0; j >>= 1) {
      if (t < 128) {
        const int i = ((t & ~(j - 1)) << 1) | (t & (j - 1));
        const int p2 = i | j;
        const bool dir = ((i & k) == 0);
        float sa = s_[i], sb = s_[p2];
        int   ia = i_[i], ib = i_[p2];
        const bool inorder = (sa > sb) || (sa == sb && ia <= ib);
        if (inorder != dir) { s_[i] = sb; s_[p2] = sa; i_[i] = ib; i_[p2] = ia; }
      }
      __syncthreads();
    }
  }

  if (t < 64) {
    float sv = s_[t];
    float mx = sv;
    #pragma unroll
    for (int off = 32; off; off >>= 1) mx = fmaxf(mx, __shfl_xor(mx, off));
    float e = expf(sv - mx);
    float zz = e;
    #pragma unroll
    for (int off = 32; off; off >>= 1) zz += __shfl_xor(zz, off);
    wsm[t] = e / zz;
    widx[t] = i_[t];
  }
  __syncthreads();

  if (t < 128) {
    float a = 0.f;
    #pragma unroll 4
    for (int k2 = 0; k2 < 64; ++k2)
      a = fmaf(wsm[k2], Vp[(size_t)widx[k2] * 512 + h * 128 + t], a);
    att[(size_t)b * 512 + h * 128 + t] = a;
  }
}

// ---------------------------------------------------------------------------
extern "C" void kernel_launch(void* const* d_in, const int* in_sizes, int n_in,
                              void* d_out, int out_size, void* d_ws, size_t ws_size,
                              hipStream_t stream) {
  const float* query  = (const float*)d_in[0];
  const float* memory = (const float*)d_in[1];
  const float* Wq = (const float*)d_in[2];
  const float* bq = (const float*)d_in[3];
  const float* Wk = (const float*)d_in[4];
  const float* bk = (const float*)d_in[5];
  const float* Wv = (const float*)d_in[6];
  const float* bv = (const float*)d_in[7];
  const float* Wo = (const float*)d_in[8];
  const float* bo = (const float*)d_in[9];
  float* out = (float*)d_out;

  // workspace layout
  float*  Qp  = (float*)d_ws;                            //  4 MB
  float*  Kp  = Qp + (size_t)B_ * D_;                    // 64 MB
  float*  Vp  = Kp + (size_t)M_ * D_;                    // 64 MB
  int*    tki = (int*)(Vp + (size_t)M_ * D_);            //  8 MB (B*H*256)
  ushort* Qbf = (ushort*)(tki + (size_t)B_ * H_ * 256);  //  2 MB
  ushort* Kbf = Qbf + (size_t)H_ * B_ * 128;             // 32 MB
  float*  att = (float*)Kbf;   // Kbf dead after pass 1; att 4 MB aliases it

  gemm_nt_bias<<<dim3(B_ / 128, 4), 256, 0, stream>>>(query,  Wq, bq, Qp, B_);
  gemm_nt_bias<<<dim3(M_ / 128, 4), 256, 0, stream>>>(memory, Wk, bk, Kp, M_);
  gemm_nt_bias<<<dim3(M_ / 128, 4), 256, 0, stream>>>(memory, Wv, bv, Vp, M_);

  to_bf16_heads<<<dim3((B_ * 64 + 255) / 256), 256, 0, stream>>>(Qp, Qbf, B_);
  to_bf16_heads<<<dim3((M_ * 64 + 255) / 256), 256, 0, stream>>>(Kp, Kbf, M_);

  scores_topk_mfma<<<dim3(B_ / 32, H_, MS_), 256, 0, stream>>>(Qbf, Kbf, tki);
  rescore_attend<<<dim3(B_ * H_), 256, 0, stream>>>(Qp, Kp, Vp, tki, att);

  gemm_nt_bias<<<dim3(B_ / 128, 4), 256, 0, stream>>>(att, Wo, bo, out, B_);
}